// Round 4
// baseline (645.885 us; speedup 1.0000x reference)
//
#include <hip/hip_runtime.h>
#include <math.h>

#define TPB 256
#define F_IN 1433
#define KPAD 1440          // 45 * 32, zero-padded tail
#define NT 45              // total k-tiles of 32 floats
#define NFULL 44           // tiles in the pipelined loop (k 0..1407); tail tile masked
#define BROWS 64           // rows per block (16 per wave)

typedef __attribute__((ext_vector_type(8))) short bf16x8;
typedef __attribute__((ext_vector_type(4))) float f32x4;

static __device__ __forceinline__ short f2bf(float f) {
    unsigned u = __float_as_uint(f);
    unsigned r = (u + 0x7FFFu + ((u >> 16) & 1u)) >> 16;   // RNE
    return (short)r;
}

// Build W^T bf16 once + zero the degree counters.
// WT[col][k]: col 0..7 = w1[0][k][col], 8..15 = w1[1][k][col-8], 16..23 = root1[k][col-16],
// 24..31 = 0; k in [F_IN, KPAD) zero-padded.
__global__ __launch_bounds__(256) void prep_kernel(
    const float* __restrict__ w1, const float* __restrict__ root1,
    short* __restrict__ WT, int* __restrict__ cnt, int N)
{
    int i = blockIdx.x * 256 + threadIdx.x;
    if (i < N) cnt[i] = 0;
    if (i < 32 * KPAD) {
        int col = i / KPAD, k = i - col * KPAD;
        float v = 0.f;
        if (k < F_IN) {
            if (col < 8)       v = w1[(size_t)k * 8 + col];
            else if (col < 16) v = w1[(size_t)(F_IN + k) * 8 + (col - 8)];
            else if (col < 24) v = root1[(size_t)k * 8 + (col - 16)];
        }
        WT[i] = f2bf(v);
    }
}

// ---------------- Fused: layer-1 GEMM (reg-direct depth-4 pipeline, 16 rows/wave,
// no LDS on the load path) for blocks < NB1; dst-histogram for the rest.
__global__ __launch_bounds__(256) void node1_hist_kernel(
    const float* __restrict__ x,      // [N][1433]
    const short* __restrict__ WT,     // [32][KPAD] bf16 (pre-transposed weights)
    const float* __restrict__ att1,   // [16]
    float* __restrict__ XW1,          // [N][16]
    float* __restrict__ H1,           // [N][8]
    float2* __restrict__ SC1,
    float* __restrict__ HA1,
    const int* __restrict__ ei,       // [2][E]
    int* __restrict__ cnt,            // [N]
    int N, int E, int NB1)
{
    __shared__ float dump[BROWS * 25];   // 6.4 KB, epilogue only

    const int tid = threadIdx.x;
    const int bid = blockIdx.x;

    if (bid >= NB1) {   // -------- histogram path
        int e = (bid - NB1) * TPB + tid;
        if (e < E) atomicAdd(&cnt[ei[(size_t)E + e]], 1);
        return;
    }

    const int wv   = tid >> 6;
    const int lane = tid & 63;
    const int rowbase = bid * BROWS;

    // A-fragment mapping (16x16x32 bf16, m89-verified): row = lane&15, k = (lane>>4)*8..+7
    const int r0 = lane & 15;
    const int kg = lane >> 4;            // 0..3
    const int klane = kg * 8;
    int rr = rowbase + wv * 16 + r0;
    if (rr >= N) rr = N - 1;
    const float* xr = x + (size_t)rr * F_IN;
    // B-fragment: col = lane&15 (+16 for second out-tile), same k
    const short* wt0 = WT + (size_t)r0 * KPAD + klane;
    const short* wt1 = wt0 + 16 * KPAD;

    f32x4 acc0, acc1;
#pragma unroll
    for (int r = 0; r < 4; ++r) { acc0[r] = 0.f; acc1[r] = 0.f; }

#define LOADT(t, Aa, Ab, Ba, Bb) do {                                          \
        const float* p_ = xr + (t) * 32 + klane;                               \
        Aa = *reinterpret_cast<const float4*>(p_);                             \
        Ab = *reinterpret_cast<const float4*>(p_ + 4);                         \
        Ba = *reinterpret_cast<const bf16x8*>(wt0 + (t) * 32);                 \
        Bb = *reinterpret_cast<const bf16x8*>(wt1 + (t) * 32);                 \
    } while (0)

#define COMP(Aa, Ab, Ba, Bb) do {                                              \
        bf16x8 pa_;                                                            \
        pa_[0] = f2bf(Aa.x); pa_[1] = f2bf(Aa.y);                              \
        pa_[2] = f2bf(Aa.z); pa_[3] = f2bf(Aa.w);                              \
        pa_[4] = f2bf(Ab.x); pa_[5] = f2bf(Ab.y);                              \
        pa_[6] = f2bf(Ab.z); pa_[7] = f2bf(Ab.w);                              \
        acc0 = __builtin_amdgcn_mfma_f32_16x16x32_bf16(pa_, Ba, acc0, 0, 0, 0);\
        acc1 = __builtin_amdgcn_mfma_f32_16x16x32_bf16(pa_, Bb, acc1, 0, 0, 0);\
    } while (0)

    // Depth-4 static register rotation (no runtime-indexed arrays -> no scratch).
    float4 A00, A01, A10, A11, A20, A21, A30, A31;
    bf16x8 B00, B01, B10, B11, B20, B21, B30, B31;

    LOADT(0, A00, A01, B00, B01);
    LOADT(1, A10, A11, B10, B11);
    LOADT(2, A20, A21, B20, B21);
    LOADT(3, A30, A31, B30, B31);

    for (int t = 0; t < NFULL; t += 4) {      // NFULL = 44 = 4 * 11
        COMP(A00, A01, B00, B01);
        if (t + 4 < NFULL) LOADT(t + 4, A00, A01, B00, B01);
        COMP(A10, A11, B10, B11);
        if (t + 5 < NFULL) LOADT(t + 5, A10, A11, B10, B11);
        COMP(A20, A21, B20, B21);
        if (t + 6 < NFULL) LOADT(t + 6, A20, A21, B20, B21);
        COMP(A30, A31, B30, B31);
        if (t + 7 < NFULL) LOADT(t + 7, A30, A31, B30, B31);
    }
#undef LOADT
#undef COMP

    // ---- tail tile (k 1408..1432): masked per-lane register loads
    {
        const int kf = NFULL * 32 + klane;
        bf16x8 pa;
#pragma unroll
        for (int q = 0; q < 8; ++q) {
            float v = (kf + q < F_IN) ? xr[kf + q] : 0.f;
            pa[q] = f2bf(v);
        }
        bf16x8 b0 = *reinterpret_cast<const bf16x8*>(wt0 + NFULL * 32);
        bf16x8 b1 = *reinterpret_cast<const bf16x8*>(wt1 + NFULL * 32);
        acc0 = __builtin_amdgcn_mfma_f32_16x16x32_bf16(pa, b0, acc0, 0, 0, 0);
        acc1 = __builtin_amdgcn_mfma_f32_16x16x32_bf16(pa, b1, acc1, 0, 0, 0);
    }

    // dump accs: C/D layout col=lane&15, row=(lane>>4)*4+reg  [m89-verified]
#pragma unroll
    for (int ot = 0; ot < 2; ++ot) {
        int col = ot * 16 + (lane & 15);
        if (col < 24) {
#pragma unroll
            for (int r = 0; r < 4; ++r) {
                int row = wv * 16 + kg * 4 + r;
                dump[row * 25 + col] = (ot == 0) ? acc0[r] : acc1[r];
            }
        }
    }
    __syncthreads();

    if (tid < BROWS) {
        int n = rowbase + tid;
        if (n < N) {
            float sum[24];
#pragma unroll
            for (int j = 0; j < 24; ++j) sum[j] = dump[tid * 25 + j];
            float s0 = 0.f, s1 = 0.f, ha = 0.f;
#pragma unroll
            for (int j = 0; j < 8; ++j) {
                s0 += sum[j] * att1[j];
                s1 += sum[8 + j] * att1[j];
                ha += sum[16 + j] * att1[8 + j];
            }
            float4* xwout = reinterpret_cast<float4*>(XW1 + (size_t)n * 16);
            xwout[0] = make_float4(sum[0], sum[1], sum[2], sum[3]);
            xwout[1] = make_float4(sum[4], sum[5], sum[6], sum[7]);
            xwout[2] = make_float4(sum[8], sum[9], sum[10], sum[11]);
            xwout[3] = make_float4(sum[12], sum[13], sum[14], sum[15]);
            float4* hout = reinterpret_cast<float4*>(H1 + (size_t)n * 8);
            hout[0] = make_float4(sum[16], sum[17], sum[18], sum[19]);
            hout[1] = make_float4(sum[20], sum[21], sum[22], sum[23]);
            SC1[n] = make_float2(s0, s1);
            HA1[n] = ha;
        }
    }
}

__global__ __launch_bounds__(256) void scanA_kernel(
    const int* __restrict__ cnt, int* __restrict__ rowptr, int* __restrict__ bsums, int N)
{
    __shared__ int lds[256];
    int t = threadIdx.x;
    int base = blockIdx.x * 1024 + t * 4;
    int c[4];
#pragma unroll
    for (int j = 0; j < 4; ++j) c[j] = (base + j < N) ? cnt[base + j] : 0;
    int tsum = c[0] + c[1] + c[2] + c[3];
    lds[t] = tsum;
    __syncthreads();
    for (int off = 1; off < 256; off <<= 1) {
        int v = (t >= off) ? lds[t - off] : 0;
        __syncthreads();
        lds[t] += v;
        __syncthreads();
    }
    int run = lds[t] - tsum;
#pragma unroll
    for (int j = 0; j < 4; ++j) {
        if (base + j < N) rowptr[base + j] = run;
        run += c[j];
    }
    if (t == 255) bsums[blockIdx.x] = lds[255];
}

__global__ __launch_bounds__(128) void scanB_kernel(int* __restrict__ bsums, int nb)
{
    __shared__ int lds[128];
    int t = threadIdx.x;
    int v = (t < nb) ? bsums[t] : 0;
    lds[t] = v;
    __syncthreads();
    for (int off = 1; off < 128; off <<= 1) {
        int w = (t >= off) ? lds[t - off] : 0;
        __syncthreads();
        lds[t] += w;
        __syncthreads();
    }
    if (t < nb) bsums[t] = lds[t] - v;
}

__global__ __launch_bounds__(256) void scanC_kernel(
    int* __restrict__ rowptr, int* __restrict__ cnt, const int* __restrict__ bsums, int N, int E)
{
    int i = blockIdx.x * TPB + threadIdx.x;
    if (i < N) {
        int v = rowptr[i] + bsums[i >> 10];
        rowptr[i] = v;
        cnt[i] = v;
    }
    if (i == 0) rowptr[N] = E;
}

__global__ __launch_bounds__(256) void scatter_kernel(
    const int* __restrict__ ei, const float* __restrict__ pseudo,
    int* __restrict__ cursor, int2* __restrict__ recs, int E)
{
    int e = blockIdx.x * TPB + threadIdx.x;
    if (e >= E) return;
    int s = ei[e];
    int d = ei[(size_t)E + e];
    float u = pseudo[e];
    int pos = atomicAdd(&cursor[d], 1);
    recs[pos] = make_int2(s, __float_as_int(u));
}

// ---------------- Gather layer-1 (16 lanes per node) + fused node2 epilogue
__global__ __launch_bounds__(256) void gather1_kernel(
    const int* __restrict__ rowptr, const int2* __restrict__ recs,
    const float4* __restrict__ XW1v,
    const float2* __restrict__ SC1, const float* __restrict__ HA1,
    const float* __restrict__ H1, const float* __restrict__ bias1,
    const float* __restrict__ w2, const float* __restrict__ root2, const float* __restrict__ att2,
    float* __restrict__ XW2, float* __restrict__ H2, float2* __restrict__ SC2, float* __restrict__ HA2,
    int N)
{
    int tid = blockIdx.x * TPB + threadIdx.x;
    int n = tid >> 4;
    int lane = tid & 15;
    if (n >= N) return;
    int start = rowptr[n], end = rowptr[n + 1];
    float ha = HA1[n];
    float den = 0.f;
    float num[8];
#pragma unroll
    for (int j = 0; j < 8; ++j) num[j] = 0.f;

    for (int i = start + lane; i < end; i += 16) {
        int2 r = recs[i];
        int s = r.x;
        float u = __int_as_float(r.y);
        float um = 1.f - u;
        float2 sc = SC1[s];
        float raw = um * sc.x + u * sc.y + ha;
        float score = (raw > 0.f) ? raw : 0.2f * raw;
        float w = __expf(score);
        const float4* xw = XW1v + (size_t)s * 4;
        float4 p0 = xw[0], p1 = xw[1], q0 = xw[2], q1 = xw[3];
        num[0] = fmaf(w, um * p0.x + u * q0.x, num[0]);
        num[1] = fmaf(w, um * p0.y + u * q0.y, num[1]);
        num[2] = fmaf(w, um * p0.z + u * q0.z, num[2]);
        num[3] = fmaf(w, um * p0.w + u * q0.w, num[3]);
        num[4] = fmaf(w, um * p1.x + u * q1.x, num[4]);
        num[5] = fmaf(w, um * p1.y + u * q1.y, num[5]);
        num[6] = fmaf(w, um * p1.z + u * q1.z, num[6]);
        num[7] = fmaf(w, um * p1.w + u * q1.w, num[7]);
        den += w;
    }
#pragma unroll
    for (int off = 1; off < 16; off <<= 1) {
#pragma unroll
        for (int j = 0; j < 8; ++j) num[j] += __shfl_xor(num[j], off);
        den += __shfl_xor(den, off);
    }
    if (lane != 0) return;

    float inv = 1.f / (den + 1e-16f);
    float hp[8];
#pragma unroll
    for (int j = 0; j < 8; ++j) {
        float o = num[j] * inv + H1[(size_t)n * 8 + j] + bias1[j];
        hp[j] = (o > 0.f) ? o : expm1f(o);
    }
    float a[7], b[7], h[7];
#pragma unroll
    for (int j2 = 0; j2 < 7; ++j2) { a[j2] = 0.f; b[j2] = 0.f; h[j2] = 0.f; }
#pragma unroll
    for (int j = 0; j < 8; ++j) {
#pragma unroll
        for (int j2 = 0; j2 < 7; ++j2) {
            a[j2] = fmaf(hp[j], w2[j * 7 + j2], a[j2]);
            b[j2] = fmaf(hp[j], w2[56 + j * 7 + j2], b[j2]);
            h[j2] = fmaf(hp[j], root2[j * 7 + j2], h[j2]);
        }
    }
    float s0 = 0.f, s1 = 0.f, hA = 0.f;
#pragma unroll
    for (int j2 = 0; j2 < 7; ++j2) {
        s0 += a[j2] * att2[j2];
        s1 += b[j2] * att2[j2];
        hA += h[j2] * att2[7 + j2];
    }
    float4* xwout = reinterpret_cast<float4*>(XW2 + (size_t)n * 16);
    xwout[0] = make_float4(a[0], a[1], a[2], a[3]);
    xwout[1] = make_float4(a[4], a[5], a[6], 0.f);
    xwout[2] = make_float4(b[0], b[1], b[2], b[3]);
    xwout[3] = make_float4(b[4], b[5], b[6], 0.f);
    float4* hout = reinterpret_cast<float4*>(H2 + (size_t)n * 8);
    hout[0] = make_float4(h[0], h[1], h[2], h[3]);
    hout[1] = make_float4(h[4], h[5], h[6], 0.f);
    SC2[n] = make_float2(s0, s1);
    HA2[n] = hA;
}

// ---------------- Gather layer-2 (16 lanes per node) + fused log_softmax
__global__ __launch_bounds__(256) void gather2_kernel(
    const int* __restrict__ rowptr, const int2* __restrict__ recs,
    const float4* __restrict__ XW2v,
    const float2* __restrict__ SC2, const float* __restrict__ HA2,
    const float* __restrict__ H2, const float* __restrict__ bias2,
    float* __restrict__ out, int N)
{
    int tid = blockIdx.x * TPB + threadIdx.x;
    int n = tid >> 4;
    int lane = tid & 15;
    if (n >= N) return;
    int start = rowptr[n], end = rowptr[n + 1];
    float ha = HA2[n];
    float den = 0.f;
    float num[7];
#pragma unroll
    for (int j = 0; j < 7; ++j) num[j] = 0.f;

    for (int i = start + lane; i < end; i += 16) {
        int2 r = recs[i];
        int s = r.x;
        float u = __int_as_float(r.y);
        float um = 1.f - u;
        float2 sc = SC2[s];
        float raw = um * sc.x + u * sc.y + ha;
        float score = (raw > 0.f) ? raw : 0.2f * raw;
        float w = __expf(score);
        const float4* xw = XW2v + (size_t)s * 4;
        float4 p0 = xw[0], p1 = xw[1], q0 = xw[2], q1 = xw[3];
        num[0] = fmaf(w, um * p0.x + u * q0.x, num[0]);
        num[1] = fmaf(w, um * p0.y + u * q0.y, num[1]);
        num[2] = fmaf(w, um * p0.z + u * q0.z, num[2]);
        num[3] = fmaf(w, um * p0.w + u * q0.w, num[3]);
        num[4] = fmaf(w, um * p1.x + u * q1.x, num[4]);
        num[5] = fmaf(w, um * p1.y + u * q1.y, num[5]);
        num[6] = fmaf(w, um * p1.z + u * q1.z, num[6]);
        den += w;
    }
#pragma unroll
    for (int off = 1; off < 16; off <<= 1) {
#pragma unroll
        for (int j = 0; j < 7; ++j) num[j] += __shfl_xor(num[j], off);
        den += __shfl_xor(den, off);
    }
    if (lane != 0) return;

    float inv = 1.f / (den + 1e-16f);
    float o[7];
    float mx = -1e30f;
#pragma unroll
    for (int j = 0; j < 7; ++j) {
        o[j] = fmaf(num[j], inv, H2[(size_t)n * 8 + j] + bias2[j]);
        mx = fmaxf(mx, o[j]);
    }
    float sum = 0.f;
#pragma unroll
    for (int j = 0; j < 7; ++j) sum += __expf(o[j] - mx);
    float lse = mx + __logf(sum);
#pragma unroll
    for (int j = 0; j < 7; ++j) out[(size_t)n * 7 + j] = o[j] - lse;
}

extern "C" void kernel_launch(void* const* d_in, const int* in_sizes, int n_in,
                              void* d_out, int out_size, void* d_ws, size_t ws_size,
                              hipStream_t stream) {
    const float* x      = (const float*)d_in[0];
    const int*   ei     = (const int*)d_in[1];
    const float* pseudo = (const float*)d_in[2];
    const float* w1     = (const float*)d_in[3];
    const float* root1  = (const float*)d_in[4];
    const float* att1   = (const float*)d_in[5];
    const float* bias1  = (const float*)d_in[6];
    const float* w2     = (const float*)d_in[7];
    const float* root2  = (const float*)d_in[8];
    const float* att2   = (const float*)d_in[9];
    const float* bias2  = (const float*)d_in[10];

    const int N = in_sizes[0] / F_IN;
    const int E = in_sizes[2];
    const size_t Ns = (size_t)N;

    float* ws   = (float*)d_ws;
    float* XW1  = ws;                       // 16N
    float* H1   = XW1 + 16 * Ns;            // 8N
    float2* SC1 = (float2*)(H1 + 8 * Ns);   // 2N floats
    float* HA1  = (float*)SC1 + 2 * Ns;     // N
    float* XW2  = HA1 + Ns;                 // 16N
    float* H2   = XW2 + 16 * Ns;            // 8N
    float2* SC2 = (float2*)(H2 + 8 * Ns);   // 2N
    float* HA2  = (float*)SC2 + 2 * Ns;     // N
    int*   cnt    = (int*)(HA2 + Ns);       // N
    int*   rowptr = cnt + Ns;               // N+1
    int*   bsums  = rowptr + Ns + 1;        // 128
    size_t off = (size_t)(bsums + 128) - (size_t)d_ws;
    off = (off + 7) & ~(size_t)7;
    int2*  recs = (int2*)((char*)d_ws + off);  // E records
    size_t woff = off + (size_t)E * sizeof(int2);
    woff = (woff + 15) & ~(size_t)15;
    short* WT = (short*)((char*)d_ws + woff);  // 32*KPAD bf16 (92 KB)

    int nblk  = (N + TPB - 1) / TPB;
    int eblk  = (E + TPB - 1) / TPB;
    int sblkA = (N + 1023) / 1024;
    int nb1   = (N + BROWS - 1) / BROWS;
    int gblk  = ((N * 16) + TPB - 1) / TPB;
    int prepn = (32 * KPAD > N) ? 32 * KPAD : N;
    int pblk  = (prepn + TPB - 1) / TPB;

    prep_kernel<<<pblk, TPB, 0, stream>>>(w1, root1, WT, cnt, N);
    node1_hist_kernel<<<nb1 + eblk, TPB, 0, stream>>>(
        x, WT, att1, XW1, H1, SC1, HA1, ei, cnt, N, E, nb1);
    scanA_kernel<<<sblkA, TPB, 0, stream>>>(cnt, rowptr, bsums, N);
    scanB_kernel<<<1, 128, 0, stream>>>(bsums, sblkA);
    scanC_kernel<<<nblk, TPB, 0, stream>>>(rowptr, cnt, bsums, N, E);
    scatter_kernel<<<eblk, TPB, 0, stream>>>(ei, pseudo, cnt, recs, E);
    gather1_kernel<<<gblk, TPB, 0, stream>>>(rowptr, recs, (const float4*)XW1, SC1, HA1,
                                             H1, bias1, w2, root2, att2,
                                             XW2, H2, SC2, HA2, N);
    gather2_kernel<<<gblk, TPB, 0, stream>>>(rowptr, recs, (const float4*)XW2, SC2, HA2,
                                             H2, bias2, (float*)d_out, N);
}

// Round 5
// 631.480 us; speedup vs baseline: 1.0228x; 1.0228x over previous
//
#include <hip/hip_runtime.h>
#include <math.h>

#define TPB 256
#define F_IN 1433
#define KPAD 1440          // 45 * 32, zero-padded tail
#define NCH 11             // full 128-float k-chunks (k 0..1407)
#define TK 1408            // tail start
#define BROWS 64           // rows per block (16 per wave)

typedef __attribute__((ext_vector_type(8))) short bf16x8;
typedef __attribute__((ext_vector_type(4))) float f32x4;

static __device__ __forceinline__ short f2bf(float f) {
    unsigned u = __float_as_uint(f);
    unsigned r = (u + 0x7FFFu + ((u >> 16) & 1u)) >> 16;   // RNE
    return (short)r;
}

static __device__ __forceinline__ void gl2lds16(const float* g, float* l) {
    __builtin_amdgcn_global_load_lds(
        (const __attribute__((address_space(1))) void*)g,
        (__attribute__((address_space(3))) void*)l,
        16, 0, 0);
}

// Build W^T bf16 once + zero the degree counters.
// WT[col][k]: col 0..7 = w1[0][k][col], 8..15 = w1[1][k][col-8], 16..23 = root1[k][col-16],
// 24..31 = 0; k in [F_IN, KPAD) zero-padded.
__global__ __launch_bounds__(256) void prep_kernel(
    const float* __restrict__ w1, const float* __restrict__ root1,
    short* __restrict__ WT, int* __restrict__ cnt, int N)
{
    int i = blockIdx.x * 256 + threadIdx.x;
    if (i < N) cnt[i] = 0;
    if (i < 32 * KPAD) {
        int col = i / KPAD, k = i - col * KPAD;
        float v = 0.f;
        if (k < F_IN) {
            if (col < 8)       v = w1[(size_t)k * 8 + col];
            else if (col < 16) v = w1[(size_t)(F_IN + k) * 8 + (col - 8)];
            else if (col < 24) v = root1[(size_t)k * 8 + (col - 16)];
        }
        WT[i] = f2bf(v);
    }
}

// ---------------- Fused: layer-1 GEMM for blocks < NB1; dst-histogram for the rest.
// GEMM: 16 rows/wave, K-chunk=128 floats. global_load_lds DMA where each of 8
// instructions covers 2 rows x 512 B CONTIGUOUS global segments (the fix target:
// prior rounds' 16-128 B segments capped HBM at ~2.2 TB/s). Wave-private double
// buffer, zero barriers, uniform counted s_waitcnt vmcnt(16). K-order within each
// row's 512 B chunk is XOR-swizzled at the GLOBAL source (rule #21) so LDS reads
// are low-conflict while the DMA dest stays linear.
__global__ __launch_bounds__(256) void node1_hist_kernel(
    const float* __restrict__ x,      // [N][1433]
    const short* __restrict__ WT,     // [32][KPAD] bf16
    const float* __restrict__ att1,   // [16]
    float* __restrict__ XW1,          // [N][16]
    float* __restrict__ H1,           // [N][8]
    float2* __restrict__ SC1,
    float* __restrict__ HA1,
    const int* __restrict__ ei,       // [2][E]
    int* __restrict__ cnt,            // [N]
    int N, int E, int NB1)
{
    // [wave][dbuf][16 rows * 128 floats] = 64 KB. Row r of a chunk lives at floats
    // [r*128, r*128+128) with within-row position s*32+m*8+low holding global float
    // s*32 + (m ^ (r&3))*8 + low of the chunk. Reused as epilogue dump (1600 f32).
    __shared__ float xb[4][2][2048];

    const int tid = threadIdx.x;
    const int bid = blockIdx.x;

    if (bid >= NB1) {   // -------- histogram path
        int e = (bid - NB1) * TPB + tid;
        if (e < E) atomicAdd(&cnt[ei[(size_t)E + e]], 1);
        return;
    }

    const int wv   = tid >> 6;
    const int lane = tid & 63;
    const int rowbase = bid * BROWS + wv * 16;

    // ---- DMA source map: instruction i covers rows i*2 + (lane>>5); 16B unit u=lane&31
    const int half = lane >> 5;
    const int u    = lane & 31;
    const int su   = u >> 3;
    const int mu   = (u >> 1) & 3;
    const int lowb = (u & 1) * 4;
    const float* dsrc[8];
#pragma unroll
    for (int i = 0; i < 8; ++i) {
        int rl = i * 2 + half;
        int r = rowbase + rl; if (r >= N) r = N - 1;
        int goff = su * 32 + ((mu ^ (rl & 3)) * 8) + lowb;   // swizzled k-order
        dsrc[i] = x + (size_t)r * F_IN + goff;
    }

#define ISSUE(c, buf) do {                                                      \
        float* lb_ = &xb[wv][buf][0];                                           \
        _Pragma("unroll")                                                       \
        for (int i = 0; i < 8; ++i)                                             \
            gl2lds16(dsrc[i] + (c) * 128, lb_ + i * 256);                       \
    } while (0)

    // ---- compute-side maps (16x16x32 bf16, m89-verified)
    const int r0 = lane & 15;
    const int kg = lane >> 4;                         // 0..3
    const int aoff = r0 * 128 + ((kg ^ (r0 & 3)) * 8);
    const short* wt0 = WT + (size_t)r0 * KPAD + kg * 8;
    const short* wt1 = wt0 + 16 * KPAD;

#define WTLOAD(c, W) do {                                                       \
        _Pragma("unroll")                                                       \
        for (int s = 0; s < 4; ++s) {                                           \
            W[s][0] = *reinterpret_cast<const bf16x8*>(wt0 + (c) * 128 + s * 32); \
            W[s][1] = *reinterpret_cast<const bf16x8*>(wt1 + (c) * 128 + s * 32); \
        }                                                                       \
    } while (0)

    f32x4 acc0, acc1;
#pragma unroll
    for (int r = 0; r < 4; ++r) { acc0[r] = 0.f; acc1[r] = 0.f; }

    bf16x8 WA[4][2], WB[4][2];

    // Prologue (issue order pinned; vmcnt accounting: 16 ops newer than ISSUE(0))
    ISSUE(0, 0);
    __builtin_amdgcn_sched_barrier(0);
    ISSUE(1, 1);
    __builtin_amdgcn_sched_barrier(0);
    WTLOAD(0, WA);

    // Per chunk c: wait vmcnt(16) [exactly ISSUE(c+1)x8 + WT(c)x8 are newer than
    // ISSUE(c), in FIFO order], ds_read all 4 A-fragment pairs, lgkmcnt(0) (WAR
    // fence), DMA chunk c+2 into the buffer just read, prefetch WT(c+1), compute.
#define CHUNK(c, buf, Wcur, Wnxt) do {                                          \
        asm volatile("s_waitcnt vmcnt(16)" ::: "memory");                       \
        const float* Bb_ = &xb[wv][buf][0];                                     \
        float4 fa0 = *reinterpret_cast<const float4*>(Bb_ + aoff + 0 * 32);     \
        float4 fb0 = *reinterpret_cast<const float4*>(Bb_ + aoff + 0 * 32 + 4); \
        float4 fa1 = *reinterpret_cast<const float4*>(Bb_ + aoff + 1 * 32);     \
        float4 fb1 = *reinterpret_cast<const float4*>(Bb_ + aoff + 1 * 32 + 4); \
        float4 fa2 = *reinterpret_cast<const float4*>(Bb_ + aoff + 2 * 32);     \
        float4 fb2 = *reinterpret_cast<const float4*>(Bb_ + aoff + 2 * 32 + 4); \
        float4 fa3 = *reinterpret_cast<const float4*>(Bb_ + aoff + 3 * 32);     \
        float4 fb3 = *reinterpret_cast<const float4*>(Bb_ + aoff + 3 * 32 + 4); \
        asm volatile("s_waitcnt lgkmcnt(0)" ::: "memory");                      \
        if ((c) + 2 < NCH) { ISSUE((c) + 2, buf); }                             \
        if ((c) + 1 < NCH) { WTLOAD((c) + 1, Wnxt); }                           \
        bf16x8 pa;                                                              \
        pa[0]=f2bf(fa0.x); pa[1]=f2bf(fa0.y); pa[2]=f2bf(fa0.z); pa[3]=f2bf(fa0.w); \
        pa[4]=f2bf(fb0.x); pa[5]=f2bf(fb0.y); pa[6]=f2bf(fb0.z); pa[7]=f2bf(fb0.w); \
        acc0 = __builtin_amdgcn_mfma_f32_16x16x32_bf16(pa, Wcur[0][0], acc0, 0, 0, 0); \
        acc1 = __builtin_amdgcn_mfma_f32_16x16x32_bf16(pa, Wcur[0][1], acc1, 0, 0, 0); \
        pa[0]=f2bf(fa1.x); pa[1]=f2bf(fa1.y); pa[2]=f2bf(fa1.z); pa[3]=f2bf(fa1.w); \
        pa[4]=f2bf(fb1.x); pa[5]=f2bf(fb1.y); pa[6]=f2bf(fb1.z); pa[7]=f2bf(fb1.w); \
        acc0 = __builtin_amdgcn_mfma_f32_16x16x32_bf16(pa, Wcur[1][0], acc0, 0, 0, 0); \
        acc1 = __builtin_amdgcn_mfma_f32_16x16x32_bf16(pa, Wcur[1][1], acc1, 0, 0, 0); \
        pa[0]=f2bf(fa2.x); pa[1]=f2bf(fa2.y); pa[2]=f2bf(fa2.z); pa[3]=f2bf(fa2.w); \
        pa[4]=f2bf(fb2.x); pa[5]=f2bf(fb2.y); pa[6]=f2bf(fb2.z); pa[7]=f2bf(fb2.w); \
        acc0 = __builtin_amdgcn_mfma_f32_16x16x32_bf16(pa, Wcur[2][0], acc0, 0, 0, 0); \
        acc1 = __builtin_amdgcn_mfma_f32_16x16x32_bf16(pa, Wcur[2][1], acc1, 0, 0, 0); \
        pa[0]=f2bf(fa3.x); pa[1]=f2bf(fa3.y); pa[2]=f2bf(fa3.z); pa[3]=f2bf(fa3.w); \
        pa[4]=f2bf(fb3.x); pa[5]=f2bf(fb3.y); pa[6]=f2bf(fb3.z); pa[7]=f2bf(fb3.w); \
        acc0 = __builtin_amdgcn_mfma_f32_16x16x32_bf16(pa, Wcur[3][0], acc0, 0, 0, 0); \
        acc1 = __builtin_amdgcn_mfma_f32_16x16x32_bf16(pa, Wcur[3][1], acc1, 0, 0, 0); \
    } while (0)

    for (int c = 0; c < NCH; c += 2) {     // NCH = 11
        CHUNK(c, 0, WA, WB);
        if (c + 1 < NCH) CHUNK(c + 1, 1, WB, WA);
    }
#undef CHUNK
#undef WTLOAD
#undef ISSUE

    // ---- tail (k 1408..1432): masked per-lane register loads
    {
        int rr = rowbase + r0; if (rr >= N) rr = N - 1;
        const float* xr = x + (size_t)rr * F_IN;
        const int kf = TK + kg * 8;
        bf16x8 pa;
#pragma unroll
        for (int q = 0; q < 8; ++q)
            pa[q] = f2bf((kf + q < F_IN) ? xr[kf + q] : 0.f);
        bf16x8 b0 = *reinterpret_cast<const bf16x8*>(wt0 + TK);
        bf16x8 b1 = *reinterpret_cast<const bf16x8*>(wt1 + TK);
        acc0 = __builtin_amdgcn_mfma_f32_16x16x32_bf16(pa, b0, acc0, 0, 0, 0);
        acc1 = __builtin_amdgcn_mfma_f32_16x16x32_bf16(pa, b1, acc1, 0, 0, 0);
    }

    __syncthreads();   // xb reused cross-wave as dump buffer

    // dump accs: C/D layout col=lane&15, row=(lane>>4)*4+reg  [m89-verified]
    float* dump = reinterpret_cast<float*>(xb);   // 64 x 25 f32 = 6.4 KB
#pragma unroll
    for (int ot = 0; ot < 2; ++ot) {
        int col = ot * 16 + r0;
        if (col < 24) {
#pragma unroll
            for (int r = 0; r < 4; ++r) {
                int row = wv * 16 + kg * 4 + r;
                dump[row * 25 + col] = (ot == 0) ? acc0[r] : acc1[r];
            }
        }
    }
    __syncthreads();

    if (tid < BROWS) {
        int n = bid * BROWS + tid;
        if (n < N) {
            float sum[24];
#pragma unroll
            for (int j = 0; j < 24; ++j) sum[j] = dump[tid * 25 + j];
            float s0 = 0.f, s1 = 0.f, ha = 0.f;
#pragma unroll
            for (int j = 0; j < 8; ++j) {
                s0 += sum[j] * att1[j];
                s1 += sum[8 + j] * att1[j];
                ha += sum[16 + j] * att1[8 + j];
            }
            float4* xwout = reinterpret_cast<float4*>(XW1 + (size_t)n * 16);
            xwout[0] = make_float4(sum[0], sum[1], sum[2], sum[3]);
            xwout[1] = make_float4(sum[4], sum[5], sum[6], sum[7]);
            xwout[2] = make_float4(sum[8], sum[9], sum[10], sum[11]);
            xwout[3] = make_float4(sum[12], sum[13], sum[14], sum[15]);
            float4* hout = reinterpret_cast<float4*>(H1 + (size_t)n * 8);
            hout[0] = make_float4(sum[16], sum[17], sum[18], sum[19]);
            hout[1] = make_float4(sum[20], sum[21], sum[22], sum[23]);
            SC1[n] = make_float2(s0, s1);
            HA1[n] = ha;
        }
    }
}

__global__ __launch_bounds__(256) void scanA_kernel(
    const int* __restrict__ cnt, int* __restrict__ rowptr, int* __restrict__ bsums, int N)
{
    __shared__ int lds[256];
    int t = threadIdx.x;
    int base = blockIdx.x * 1024 + t * 4;
    int c[4];
#pragma unroll
    for (int j = 0; j < 4; ++j) c[j] = (base + j < N) ? cnt[base + j] : 0;
    int tsum = c[0] + c[1] + c[2] + c[3];
    lds[t] = tsum;
    __syncthreads();
    for (int off = 1; off < 256; off <<= 1) {
        int v = (t >= off) ? lds[t - off] : 0;
        __syncthreads();
        lds[t] += v;
        __syncthreads();
    }
    int run = lds[t] - tsum;
#pragma unroll
    for (int j = 0; j < 4; ++j) {
        if (base + j < N) rowptr[base + j] = run;
        run += c[j];
    }
    if (t == 255) bsums[blockIdx.x] = lds[255];
}

__global__ __launch_bounds__(128) void scanB_kernel(int* __restrict__ bsums, int nb)
{
    __shared__ int lds[128];
    int t = threadIdx.x;
    int v = (t < nb) ? bsums[t] : 0;
    lds[t] = v;
    __syncthreads();
    for (int off = 1; off < 128; off <<= 1) {
        int w = (t >= off) ? lds[t - off] : 0;
        __syncthreads();
        lds[t] += w;
        __syncthreads();
    }
    if (t < nb) bsums[t] = lds[t] - v;
}

__global__ __launch_bounds__(256) void scanC_kernel(
    int* __restrict__ rowptr, int* __restrict__ cnt, const int* __restrict__ bsums, int N, int E)
{
    int i = blockIdx.x * TPB + threadIdx.x;
    if (i < N) {
        int v = rowptr[i] + bsums[i >> 10];
        rowptr[i] = v;
        cnt[i] = v;
    }
    if (i == 0) rowptr[N] = E;
}

__global__ __launch_bounds__(256) void scatter_kernel(
    const int* __restrict__ ei, const float* __restrict__ pseudo,
    int* __restrict__ cursor, int2* __restrict__ recs, int E)
{
    int e = blockIdx.x * TPB + threadIdx.x;
    if (e >= E) return;
    int s = ei[e];
    int d = ei[(size_t)E + e];
    float u = pseudo[e];
    int pos = atomicAdd(&cursor[d], 1);
    recs[pos] = make_int2(s, __float_as_int(u));
}

// ---------------- Gather layer-1 (16 lanes per node) + fused node2 epilogue
__global__ __launch_bounds__(256) void gather1_kernel(
    const int* __restrict__ rowptr, const int2* __restrict__ recs,
    const float4* __restrict__ XW1v,
    const float2* __restrict__ SC1, const float* __restrict__ HA1,
    const float* __restrict__ H1, const float* __restrict__ bias1,
    const float* __restrict__ w2, const float* __restrict__ root2, const float* __restrict__ att2,
    float* __restrict__ XW2, float* __restrict__ H2, float2* __restrict__ SC2, float* __restrict__ HA2,
    int N)
{
    int tid = blockIdx.x * TPB + threadIdx.x;
    int n = tid >> 4;
    int lane = tid & 15;
    if (n >= N) return;
    int start = rowptr[n], end = rowptr[n + 1];
    float ha = HA1[n];
    float den = 0.f;
    float num[8];
#pragma unroll
    for (int j = 0; j < 8; ++j) num[j] = 0.f;

    for (int i = start + lane; i < end; i += 16) {
        int2 r = recs[i];
        int s = r.x;
        float u = __int_as_float(r.y);
        float um = 1.f - u;
        float2 sc = SC1[s];
        float raw = um * sc.x + u * sc.y + ha;
        float score = (raw > 0.f) ? raw : 0.2f * raw;
        float w = __expf(score);
        const float4* xw = XW1v + (size_t)s * 4;
        float4 p0 = xw[0], p1 = xw[1], q0 = xw[2], q1 = xw[3];
        num[0] = fmaf(w, um * p0.x + u * q0.x, num[0]);
        num[1] = fmaf(w, um * p0.y + u * q0.y, num[1]);
        num[2] = fmaf(w, um * p0.z + u * q0.z, num[2]);
        num[3] = fmaf(w, um * p0.w + u * q0.w, num[3]);
        num[4] = fmaf(w, um * p1.x + u * q1.x, num[4]);
        num[5] = fmaf(w, um * p1.y + u * q1.y, num[5]);
        num[6] = fmaf(w, um * p1.z + u * q1.z, num[6]);
        num[7] = fmaf(w, um * p1.w + u * q1.w, num[7]);
        den += w;
    }
#pragma unroll
    for (int off = 1; off < 16; off <<= 1) {
#pragma unroll
        for (int j = 0; j < 8; ++j) num[j] += __shfl_xor(num[j], off);
        den += __shfl_xor(den, off);
    }
    if (lane != 0) return;

    float inv = 1.f / (den + 1e-16f);
    float hp[8];
#pragma unroll
    for (int j = 0; j < 8; ++j) {
        float o = num[j] * inv + H1[(size_t)n * 8 + j] + bias1[j];
        hp[j] = (o > 0.f) ? o : expm1f(o);
    }
    float a[7], b[7], h[7];
#pragma unroll
    for (int j2 = 0; j2 < 7; ++j2) { a[j2] = 0.f; b[j2] = 0.f; h[j2] = 0.f; }
#pragma unroll
    for (int j = 0; j < 8; ++j) {
#pragma unroll
        for (int j2 = 0; j2 < 7; ++j2) {
            a[j2] = fmaf(hp[j], w2[j * 7 + j2], a[j2]);
            b[j2] = fmaf(hp[j], w2[56 + j * 7 + j2], b[j2]);
            h[j2] = fmaf(hp[j], root2[j * 7 + j2], h[j2]);
        }
    }
    float s0 = 0.f, s1 = 0.f, hA = 0.f;
#pragma unroll
    for (int j2 = 0; j2 < 7; ++j2) {
        s0 += a[j2] * att2[j2];
        s1 += b[j2] * att2[j2];
        hA += h[j2] * att2[7 + j2];
    }
    float4* xwout = reinterpret_cast<float4*>(XW2 + (size_t)n * 16);
    xwout[0] = make_float4(a[0], a[1], a[2], a[3]);
    xwout[1] = make_float4(a[4], a[5], a[6], 0.f);
    xwout[2] = make_float4(b[0], b[1], b[2], b[3]);
    xwout[3] = make_float4(b[4], b[5], b[6], 0.f);
    float4* hout = reinterpret_cast<float4*>(H2 + (size_t)n * 8);
    hout[0] = make_float4(h[0], h[1], h[2], h[3]);
    hout[1] = make_float4(h[4], h[5], h[6], 0.f);
    SC2[n] = make_float2(s0, s1);
    HA2[n] = hA;
}

// ---------------- Gather layer-2 (16 lanes per node) + fused log_softmax
__global__ __launch_bounds__(256) void gather2_kernel(
    const int* __restrict__ rowptr, const int2* __restrict__ recs,
    const float4* __restrict__ XW2v,
    const float2* __restrict__ SC2, const float* __restrict__ HA2,
    const float* __restrict__ H2, const float* __restrict__ bias2,
    float* __restrict__ out, int N)
{
    int tid = blockIdx.x * TPB + threadIdx.x;
    int n = tid >> 4;
    int lane = tid & 15;
    if (n >= N) return;
    int start = rowptr[n], end = rowptr[n + 1];
    float ha = HA2[n];
    float den = 0.f;
    float num[7];
#pragma unroll
    for (int j = 0; j < 7; ++j) num[j] = 0.f;

    for (int i = start + lane; i < end; i += 16) {
        int2 r = recs[i];
        int s = r.x;
        float u = __int_as_float(r.y);
        float um = 1.f - u;
        float2 sc = SC2[s];
        float raw = um * sc.x + u * sc.y + ha;
        float score = (raw > 0.f) ? raw : 0.2f * raw;
        float w = __expf(score);
        const float4* xw = XW2v + (size_t)s * 4;
        float4 p0 = xw[0], p1 = xw[1], q0 = xw[2], q1 = xw[3];
        num[0] = fmaf(w, um * p0.x + u * q0.x, num[0]);
        num[1] = fmaf(w, um * p0.y + u * q0.y, num[1]);
        num[2] = fmaf(w, um * p0.z + u * q0.z, num[2]);
        num[3] = fmaf(w, um * p0.w + u * q0.w, num[3]);
        num[4] = fmaf(w, um * p1.x + u * q1.x, num[4]);
        num[5] = fmaf(w, um * p1.y + u * q1.y, num[5]);
        num[6] = fmaf(w, um * p1.z + u * q1.z, num[6]);
        den += w;
    }
#pragma unroll
    for (int off = 1; off < 16; off <<= 1) {
#pragma unroll
        for (int j = 0; j < 7; ++j) num[j] += __shfl_xor(num[j], off);
        den += __shfl_xor(den, off);
    }
    if (lane != 0) return;

    float inv = 1.f / (den + 1e-16f);
    float o[7];
    float mx = -1e30f;
#pragma unroll
    for (int j = 0; j < 7; ++j) {
        o[j] = fmaf(num[j], inv, H2[(size_t)n * 8 + j] + bias2[j]);
        mx = fmaxf(mx, o[j]);
    }
    float sum = 0.f;
#pragma unroll
    for (int j = 0; j < 7; ++j) sum += __expf(o[j] - mx);
    float lse = mx + __logf(sum);
#pragma unroll
    for (int j = 0; j < 7; ++j) out[(size_t)n * 7 + j] = o[j] - lse;
}

extern "C" void kernel_launch(void* const* d_in, const int* in_sizes, int n_in,
                              void* d_out, int out_size, void* d_ws, size_t ws_size,
                              hipStream_t stream) {
    const float* x      = (const float*)d_in[0];
    const int*   ei     = (const int*)d_in[1];
    const float* pseudo = (const float*)d_in[2];
    const float* w1     = (const float*)d_in[3];
    const float* root1  = (const float*)d_in[4];
    const float* att1   = (const float*)d_in[5];
    const float* bias1  = (const float*)d_in[6];
    const float* w2     = (const float*)d_in[7];
    const float* root2  = (const float*)d_in[8];
    const float* att2   = (const float*)d_in[9];
    const float* bias2  = (const float*)d_in[10];

    const int N = in_sizes[0] / F_IN;
    const int E = in_sizes[2];
    const size_t Ns = (size_t)N;

    float* ws   = (float*)d_ws;
    float* XW1  = ws;                       // 16N
    float* H1   = XW1 + 16 * Ns;            // 8N
    float2* SC1 = (float2*)(H1 + 8 * Ns);   // 2N floats
    float* HA1  = (float*)SC1 + 2 * Ns;     // N
    float* XW2  = HA1 + Ns;                 // 16N
    float* H2   = XW2 + 16 * Ns;            // 8N
    float2* SC2 = (float2*)(H2 + 8 * Ns);   // 2N
    float* HA2  = (float*)SC2 + 2 * Ns;     // N
    int*   cnt    = (int*)(HA2 + Ns);       // N
    int*   rowptr = cnt + Ns;               // N+1
    int*   bsums  = rowptr + Ns + 1;        // 128
    size_t off = (size_t)(bsums + 128) - (size_t)d_ws;
    off = (off + 7) & ~(size_t)7;
    int2*  recs = (int2*)((char*)d_ws + off);  // E records
    size_t woff = off + (size_t)E * sizeof(int2);
    woff = (woff + 15) & ~(size_t)15;
    short* WT = (short*)((char*)d_ws + woff);  // 32*KPAD bf16 (92 KB)

    int nblk  = (N + TPB - 1) / TPB;
    int eblk  = (E + TPB - 1) / TPB;
    int sblkA = (N + 1023) / 1024;
    int nb1   = (N + BROWS - 1) / BROWS;
    int gblk  = ((N * 16) + TPB - 1) / TPB;
    int prepn = (32 * KPAD > N) ? 32 * KPAD : N;
    int pblk  = (prepn + TPB - 1) / TPB;

    prep_kernel<<<pblk, TPB, 0, stream>>>(w1, root1, WT, cnt, N);
    node1_hist_kernel<<<nb1 + eblk, TPB, 0, stream>>>(
        x, WT, att1, XW1, H1, SC1, HA1, ei, cnt, N, E, nb1);
    scanA_kernel<<<sblkA, TPB, 0, stream>>>(cnt, rowptr, bsums, N);
    scanB_kernel<<<1, 128, 0, stream>>>(bsums, sblkA);
    scanC_kernel<<<nblk, TPB, 0, stream>>>(rowptr, cnt, bsums, N, E);
    scatter_kernel<<<eblk, TPB, 0, stream>>>(ei, pseudo, cnt, recs, E);
    gather1_kernel<<<gblk, TPB, 0, stream>>>(rowptr, recs, (const float4*)XW1, SC1, HA1,
                                             H1, bias1, w2, root2, att2,
                                             XW2, H2, SC2, HA2, N);
    gather2_kernel<<<gblk, TPB, 0, stream>>>(rowptr, recs, (const float4*)XW2, SC2, HA2,
                                             H2, bias2, (float*)d_out, N);
}